// Round 4
// baseline (247.426 us; speedup 1.0000x reference)
//
#include <hip/hip_runtime.h>
#include <math.h>

#define NB 4096
#define NC 128
#define NK 32
#define NE 128

typedef __bf16 bf16x8 __attribute__((ext_vector_type(8)));
typedef float floatx4 __attribute__((ext_vector_type(4)));

__device__ __forceinline__ float sigmoidf_(float x){
  if (x >= 0.f){ float z = expf(-x); return 1.f/(1.f+z); }
  float z = expf(x); return z/(1.f+z);
}
__device__ __forceinline__ float softplusf_(float x){
  return fmaxf(x, 0.f) + log1pf(expf(-fabsf(x)));
}
__device__ __forceinline__ unsigned int pack_bf16(float a, float b){
  unsigned short ua = __builtin_bit_cast(unsigned short, (__bf16)a);
  unsigned short ub = __builtin_bit_cast(unsigned short, (__bf16)b);
  return (unsigned int)ua | ((unsigned int)ub << 16);
}

// ================= K1: hij GEMM + prio MLP + grouping + consts + w2f =========================
// R4 change: LDS reads vectorized to ds_read_b128.
//  - weight chunks wa_s/wb_s: stride 33 -> 36 (16B-aligned rows; 64 lanes x 4 dwords cover all
//    32 banks uniformly 8x = pure-BW floor, no conflict) and war/wbr consumed as float4.
//  - prio weights: wsm re-laid out as [q][132] (row-major per output unit) so each thread
//    streams its row as float4; lanes 0-31/32-63 read identical addresses (broadcast).
// fmaf chains consume identical values in identical order -> hij/prio bit-identical.
__global__ void k_hijprio(const float* __restrict__ emb, const float* __restrict__ gen,
                          const float* __restrict__ cons, const float* __restrict__ fp_w1,
                          const float* __restrict__ fp_b1, const float* __restrict__ fp_w2,
                          const float* __restrict__ ps_w1, const float* __restrict__ ps_b1,
                          const float* __restrict__ ps_w2, const float* __restrict__ ps_b2,
                          const int* __restrict__ assign, const int* __restrict__ hourp,
                          float* __restrict__ hi, float* __restrict__ hj,
                          float* __restrict__ net, float* __restrict__ prio,
                          int* __restrict__ g, int* __restrict__ row_of,
                          float* __restrict__ w1d_c, float* __restrict__ bzc,
                          uint4* __restrict__ w2f, float* __restrict__ total){
  int bid = blockIdx.x;
  int t = threadIdx.x;
  if (bid < 512){
    __shared__ float es[8*132];
    __shared__ float wsm[32*132];     // ps_w1 row-major: wsm[q*132+e] (b128-readable per thread)
    __shared__ float wa_s[128*36];    // W1a column-chunk, stride 36: 16B-aligned + bank-uniform
    __shared__ float wb_s[128*36];    // W1b column-chunk
    int i0 = bid*8;
    for (int idx = t; idx < 8*128; idx += 256){
      int b = idx >> 7, e = idx & 127;
      es[b*132 + e] = emb[(i0 + b)*128 + e];
    }
    for (int idx = t; idx < 4096; idx += 256){
      int q = idx >> 7, e = idx & 127;          // read ps_w1[q*128+e] coalesced (same as before)
      wsm[q*132 + e] = ps_w1[q*128 + e];
    }
    // ---- hij (f32, precision-critical; identical fmaf nesting, W1 values identical) ----
    int o = t & 127, half = t >> 7;
    float ai[4], aj[4];
#pragma unroll
    for (int r = 0; r < 4; ++r){ ai[r] = 0.f; aj[r] = 0.f; }
    for (int ch = 0; ch < 4; ++ch){
      int ec = ch << 5;                         // e-chunk base: 0,32,64,96
      if (ch) __syncthreads();                  // prev chunk's readers done before overwrite
      for (int idx = t; idx < 4096; idx += 256){
        int row = idx >> 5, e2 = idx & 31;      // coalesced: 32 consecutive floats per row
        wa_s[row*36 + e2] = fp_w1[row*258 + ec + e2];
        wb_s[row*36 + e2] = fp_w1[row*258 + 128 + ec + e2];
      }
      __syncthreads();                          // (ch==0 also covers es/wsm staging)
      const float* war = &wa_s[o*36];
      const float* wbr = &wb_s[o*36];
#pragma unroll
      for (int e2 = 0; e2 < 32; e2 += 4){
        float4 wav = *(const float4*)&war[e2];  // ds_read_b128 (was 4x ds_read_b32)
        float4 wbv = *(const float4*)&wbr[e2];
        float wa0 = wav.x, wa1 = wav.y, wa2 = wav.z, wa3 = wav.w;
        float wb0 = wbv.x, wb1 = wbv.y, wb2 = wbv.z, wb3 = wbv.w;
        int e = ec + e2;
#pragma unroll
        for (int r = 0; r < 4; ++r){
          float4 ev = *(const float4*)&es[(half*4 + r)*132 + e];
          ai[r] = fmaf(ev.x, wa0, fmaf(ev.y, wa1, fmaf(ev.z, wa2, fmaf(ev.w, wa3, ai[r]))));
          aj[r] = fmaf(ev.x, wb0, fmaf(ev.y, wb1, fmaf(ev.z, wb2, fmaf(ev.w, wb3, aj[r]))));
        }
      }
    }
#pragma unroll
    for (int r = 0; r < 4; ++r){
      int b = i0 + half*4 + r;
      hi[b*128 + o] = ai[r];                    // natural order — consumers gather via g
      hj[b*128 + o] = aj[r];
    }
    // ---- prio (f32 exact; same accumulation order; b128 streaming reads) ----
    {
      int bl = t >> 5, q = t & 31;
      int i = i0 + bl;
      float acc = ps_b1[q];
      const float* er = &es[bl*132];            // (132*bl)*4 bytes = 528*bl: 16B-aligned
      const float* wr = &wsm[q*132];
      for (int e = 0; e < 128; e += 4){
        float4 ev = *(const float4*)&er[e];     // broadcast across lanes (same bl)
        float4 wv = *(const float4*)&wr[e];     // b128, half-wave broadcast
        acc = fmaf(ev.x, wv.x, acc);
        acc = fmaf(ev.y, wv.y, acc);
        acc = fmaf(ev.z, wv.z, acc);
        acc = fmaf(ev.w, wv.w, acc);
      }
      float v = fmaxf(acc, 0.f) * ps_w2[q];
      for (int m = 16; m >= 1; m >>= 1) v += __shfl_xor(v, m, 32);
      if (q == 0){
        prio[i] = sigmoidf_(v + ps_b2[0]);
        int h = hourp[0];
        net[i] = gen[i*24 + h] - cons[i*24 + h];
      }
    }
  } else if (bid < 528){
    __shared__ int hist[NC];
    __shared__ int loc[256];
    int start = (bid - 512)*256;
    for (int c = t; c < NC; c += 256) hist[c] = 0;
    __syncthreads();
    for (int j = t; j < start; j += 256) atomicAdd(&hist[assign[j]], 1);
    int i = start + t;
    int c = assign[i];
    loc[t] = c;
    __syncthreads();
    int r = hist[c];
    for (int j = 0; j < 256; ++j) r += (j < t && loc[j] == c) ? 1 : 0;
    if (r >= NK) r = NK - 1;
    g[c*NK + r] = i;
    row_of[i] = c*NK + r;
  } else if (bid == 528){
    if (t < 128){
      float hour_f = (float)hourp[0] / 24.0f;
      w1d_c[t] = fp_w1[t*258 + 256];
      bzc[t]   = fmaf(hour_f, fp_w1[t*258 + 257], fp_b1[t]);
    }
    if (t == 128) total[0] = 0.f;
  } else {
    // W2 fragments: frag f=(nt*4+ks)*64+lane holds W2[o=nt*16+(lane&15)][ks*32+(lane>>4)*8 + 0..7]
    for (int ff = t; ff < 1024; ff += 256){
      int lane = ff & 63, fi = ff >> 6;
      int nt = fi >> 2, ks = fi & 3;
      int o = nt*16 + (lane & 15);
      int kb = ks*32 + (lane >> 4)*8;
      const float* src = fp_w2 + o*128 + kb;
      uint4 u;
      u.x = pack_bf16(src[0], src[1]);
      u.y = pack_bf16(src[2], src[3]);
      u.z = pack_bf16(src[4], src[5]);
      u.w = pack_bf16(src[6], src[7]);
      w2f[ff] = u;
    }
  }
}

// ================= K2a: pflow + eff on the FULL GPU (256 blocks, 2 per cluster; unchanged) ====
__global__ __launch_bounds__(512) void k_pflow(
    const float* __restrict__ hi, const float* __restrict__ hj,
    const float* __restrict__ pos, const float* __restrict__ w1d_c,
    const float* __restrict__ bzc, const uint4* __restrict__ w2f,
    const float* __restrict__ fp_b2, const float* __restrict__ fp_w3,
    const float* __restrict__ fp_b3, const float* __restrict__ en_w1,
    const float* __restrict__ en_b1, const float* __restrict__ en_w2,
    const float* __restrict__ en_b2, const int* __restrict__ g,
    float* __restrict__ pf_g, float* __restrict__ ef_g){
  __shared__ float px[32], py[32];
  __shared__ int gl[32];
  int t = threadIdx.x;
  int lane = t & 63, wv = t >> 6;
  int c = blockIdx.x >> 1, hb = blockIdx.x & 1;
  if (t < 32){
    int b = g[c*NK + t];
    gl[t] = b;
    px[t] = pos[2*b];
    py[t] = pos[2*b + 1];
  }
  __syncthreads();
  {
    int l16 = lane & 15, quad = lane >> 4;
    bf16x8 bfr[4][4];
#pragma unroll
    for (int nt = 0; nt < 4; ++nt)
#pragma unroll
      for (int ks = 0; ks < 4; ++ks)
        bfr[nt][ks] = __builtin_bit_cast(bf16x8, w2f[(nt*4 + ks)*64 + lane]);
    float b2v[4], w3v[4];
#pragma unroll
    for (int nt = 0; nt < 4; ++nt){
      b2v[nt] = fp_b2[nt*16 + l16];
      w3v[nt] = fp_w3[nt*16 + l16];
    }
    float b3 = fp_b3[0];
    const float4* wd4 = (const float4*)w1d_c;
    const float4* bz4 = (const float4*)bzc;
    for (int it = 0; it < 4; ++it){
      int tile = hb*32 + it*8 + wv;          // this block's half of the 64 tiles
      int i = tile >> 1, j0 = (tile & 1)*16;
      int j = j0 + l16;
      float dx = px[i] - px[j], dy = py[i] - py[j];
      float d = sqrtf(fmaf(dx, dx, dy*dy));
      const float4* hi4 = (const float4*)(hi + gl[i]*128);
      const float4* hj4 = (const float4*)(hj + gl[j]*128);
      bf16x8 af[4];
#pragma unroll
      for (int ks = 0; ks < 4; ++ks){
        int q8 = ks*8 + quad*2;
        float4 a0 = hi4[q8], a1 = hi4[q8 + 1];
        float4 b0 = hj4[q8], b1 = hj4[q8 + 1];
        float4 w0 = wd4[q8], w1 = wd4[q8 + 1];
        float4 z0 = bz4[q8], z1 = bz4[q8 + 1];
        float v0 = fmaxf(a0.x + b0.x + fmaf(d, w0.x, z0.x), 0.f);
        float v1 = fmaxf(a0.y + b0.y + fmaf(d, w0.y, z0.y), 0.f);
        float v2 = fmaxf(a0.z + b0.z + fmaf(d, w0.z, z0.z), 0.f);
        float v3 = fmaxf(a0.w + b0.w + fmaf(d, w0.w, z0.w), 0.f);
        float v4 = fmaxf(a1.x + b1.x + fmaf(d, w1.x, z1.x), 0.f);
        float v5 = fmaxf(a1.y + b1.y + fmaf(d, w1.y, z1.y), 0.f);
        float v6 = fmaxf(a1.z + b1.z + fmaf(d, w1.z, z1.z), 0.f);
        float v7 = fmaxf(a1.w + b1.w + fmaf(d, w1.w, z1.w), 0.f);
        uint4 u;
        u.x = pack_bf16(v0, v1);
        u.y = pack_bf16(v2, v3);
        u.z = pack_bf16(v4, v5);
        u.w = pack_bf16(v6, v7);
        af[ks] = __builtin_bit_cast(bf16x8, u);
      }
      floatx4 acc[4];
#pragma unroll
      for (int nt = 0; nt < 4; ++nt){
        acc[nt] = (floatx4){0.f, 0.f, 0.f, 0.f};
#pragma unroll
        for (int ks = 0; ks < 4; ++ks)
          acc[nt] = __builtin_amdgcn_mfma_f32_16x16x32_bf16(af[ks], bfr[nt][ks], acc[nt], 0, 0, 0);
      }
#pragma unroll
      for (int r = 0; r < 4; ++r){
        float s = 0.f;
#pragma unroll
        for (int nt = 0; nt < 4; ++nt)
          s = fmaf(fmaxf(acc[nt][r] + b2v[nt], 0.f), w3v[nt], s);
#pragma unroll
        for (int m = 8; m >= 1; m >>= 1) s += __shfl_xor(s, m);
        if (l16 == 0)
          pf_g[c*1024 + i*32 + j0 + quad*4 + r] = softplusf_(s + b3);
      }
    }
  }
  // ---- eff: this block's 512 entries (rows in its half), one per thread ----
  {
    int e = hb*512 + t;
    int ii = e >> 5, jj = e & 31;
    float dx = px[ii] - px[jj], dy = py[ii] - py[jj];
    float d = sqrtf(fmaf(dx, dx, dy*dy));
    float ds = d * (1.0f/1000.0f);
    float acc = en_b2[0];
#pragma unroll
    for (int q = 0; q < 16; ++q)
      acc = fmaf(fmaxf(fmaf(ds, en_w1[q], en_b1[q]), 0.f), en_w2[q], acc);
    ef_g[c*1024 + e] = 0.85f + 0.13f*sigmoidf_(acc);
  }
}

// ================= K2b: greedy (ranking + serial loop + writeback; unchanged) =================
__global__ __launch_bounds__(256) void k_greedy(
    const float* __restrict__ net, const float* __restrict__ prio,
    const int* __restrict__ g, const float* __restrict__ pf_g,
    const float* __restrict__ ef_g,
    float* __restrict__ fl_c, float* __restrict__ ef_c, float* __restrict__ total,
    float* __restrict__ esent, float* __restrict__ erecv, float* __restrict__ nafter){
  __shared__ float pf_s[1024];
  __shared__ float ef_s[1024];
  __shared__ float fl_s[1024];
  __shared__ float efa_s[1024];
  __shared__ int gl[32];
  __shared__ int order_s[32];
  int t = threadIdx.x;
  int c = blockIdx.x;
  if (t < 32) gl[t] = g[c*NK + t];
  // stage pf/eff (one float4 per thread each; coalesced, L2-hot)
  ((float4*)pf_s)[t] = ((const float4*)(pf_g + c*1024))[t];
  ((float4*)ef_s)[t] = ((const float4*)(ef_g + c*1024))[t];
  __syncthreads();
  if (t < 64){
    int tl = t & 31;
    float pr = (t < 32) ? prio[gl[t]] : -1e30f;
    int rank = 0;
    for (int k = 0; k < 32; ++k){
      float pk = __shfl(pr, k, 32);
      rank += ((pk > pr) || (pk == pr && k < tl)) ? 1 : 0;
    }
    if (t < 32) order_s[rank] = t;
  }
  __syncthreads();
  // ---- greedy allocation (decision math bit-identical; stores to LDS) ----
  if (t < 64){
    int tl = t & 31;
    int b = order_s[tl];
    float net0 = net[gl[b]];
    float dnet = net0;
    float recv = 0.f;
    for (int i = 0; i < 32; ++i){
      int a = order_s[i];
      float av0 = fmaxf(__shfl(net0, i, 32), 0.f);
      float pf = pf_s[a*32 + b];
      float ef = ef_s[a*32 + b];
      float needed = -dnet;
      float m = (needed > 0.f) ? fminf(needed, pf) : 0.f;
      float s = m;
#pragma unroll
      for (int dd = 1; dd < 32; dd <<= 1){
        float u = __shfl_up(s, dd, 32);
        if (tl >= dd) s += u;
      }
      float Se = __shfl_up(s, 1, 32);
      if (tl == 0) Se = 0.f;
      float rprev = fmaxf(av0 - Se, 0.f);
      int act = (rprev > 0.f) && (needed > 0.f);
      float f = fminf(m, rprev);
      dnet = fmaf(f, ef, dnet);
      recv = fmaf(f, ef, recv);
      if (t < 32){
        fl_s[a*32 + b]  = f;
        efa_s[a*32 + b] = act ? ef : 1.0f;
      }
    }
    if (t < 32){
      nafter[gl[b]] = dnet;
      erecv[gl[b]]  = recv;
    }
  }
  __syncthreads();
  // ---- parallel post-pass: coalesced writeback + esent/total (off the serial path) ----
  for (int e = t; e < 1024; e += 256){
    fl_c[c*1024 + e] = fl_s[e];
    ef_c[c*1024 + e] = efa_s[e];
  }
  if (t < 32){
    float rs = 0.f;
#pragma unroll
    for (int j = 0; j < 32; ++j)
      rs += fl_s[t*32 + ((j + t) & 31)];        // rotated -> conflict-free row sums
    esent[gl[t]] = rs;
    float cs = rs;
    for (int m = 16; m >= 1; m >>= 1) cs += __shfl_xor(cs, m, 32);
    if (t == 0) atomicAdd(total, cs);
  }
}

// ================= K3: stream N x N outputs (nontemporal stores; unchanged) ===================
__global__ __launch_bounds__(256) void k_write(
    const float* __restrict__ fl_c, const float* __restrict__ ef_c,
    const int* __restrict__ g, const int* __restrict__ row_of,
    float* __restrict__ sharing, float* __restrict__ effm){
  __shared__ float rowS[4096];
  __shared__ float rowE[4096];
  __shared__ int   cols[32];
  __shared__ float vals[32];
  __shared__ float vale[32];
  int t = threadIdx.x;
  int r = blockIdx.x;
  int ra = row_of[r];
  int c = ra >> 5, a = ra & 31;
  if (t < 32){
    cols[t] = g[c*NK + t];
    vals[t] = fl_c[c*1024 + a*32 + t];
    vale[t] = ef_c[c*1024 + a*32 + t];
  }
  float4 z4 = make_float4(0.f, 0.f, 0.f, 0.f);
  float4 o4 = make_float4(1.f, 1.f, 1.f, 1.f);
  float4* s4 = (float4*)rowS;
  float4* e4 = (float4*)rowE;
#pragma unroll
  for (int q = 0; q < 4; ++q){ s4[t + 256*q] = z4; e4[t + 256*q] = o4; }
  __syncthreads();
  if (t < 32){ rowS[cols[t]] = vals[t]; rowE[cols[t]] = vale[t]; }
  __syncthreads();
  // nontemporal stores through native ext-vector type (builtin rejects HIP float4 struct)
  const floatx4* s4v = (const floatx4*)rowS;
  const floatx4* e4v = (const floatx4*)rowE;
  floatx4* gs = (floatx4*)(sharing + (long)r*NB);
  floatx4* ge = (floatx4*)(effm    + (long)r*NB);
#pragma unroll
  for (int q = 0; q < 4; ++q){
    __builtin_nontemporal_store(s4v[t + 256*q], &gs[t + 256*q]);
    __builtin_nontemporal_store(e4v[t + 256*q], &ge[t + 256*q]);
  }
}

extern "C" void kernel_launch(void* const* d_in, const int* in_sizes, int n_in,
                              void* d_out, int out_size, void* d_ws, size_t ws_size,
                              hipStream_t stream){
  (void)in_sizes; (void)n_in; (void)out_size; (void)ws_size;
  const float* emb   = (const float*)d_in[0];
  const float* gen   = (const float*)d_in[1];
  const float* cons  = (const float*)d_in[2];
  const float* pos   = (const float*)d_in[3];
  const float* fp_w1 = (const float*)d_in[4];
  const float* fp_b1 = (const float*)d_in[5];
  const float* fp_w2 = (const float*)d_in[6];
  const float* fp_b2 = (const float*)d_in[7];
  const float* fp_w3 = (const float*)d_in[8];
  const float* fp_b3 = (const float*)d_in[9];
  const float* en_w1 = (const float*)d_in[10];
  const float* en_b1 = (const float*)d_in[11];
  const float* en_w2 = (const float*)d_in[12];
  const float* en_b2 = (const float*)d_in[13];
  const float* ps_w1 = (const float*)d_in[14];
  const float* ps_b1 = (const float*)d_in[15];
  const float* ps_w2 = (const float*)d_in[16];
  const float* ps_b2 = (const float*)d_in[17];
  const int*   assign = (const int*)d_in[18];
  const int*   hourp  = (const int*)d_in[20];

  // Workspace map (audited, no overlaps):
  char* ws = (char*)d_ws;
  int*   g      = (int*)  (ws + 0);           // [0,       16384)
  int*   row_of = (int*)  (ws + 16384);       // [16384,   32768)
  float* net    = (float*)(ws + 32768);       // [32768,   49152)
  float* prio   = (float*)(ws + 49152);       // [49152,   65536)
  float* w1d_c  = (float*)(ws + 65536);       // [65536,   66048)
  float* bzc    = (float*)(ws + 66048);       // [66048,   66560)
  uint4* w2f    = (uint4*)(ws + 131072);      // [131072,  147456)
  float* hi     = (float*)(ws + 262144);      // [262144,  2359296)
  float* hj     = (float*)(ws + 2359296);     // [2359296, 4456448)
  float* fl_c   = (float*)(ws + 4456448);     // [4456448, 4980736)
  float* ef_c   = (float*)(ws + 4980736);     // [4980736, 5505024)
  float* pf_g   = (float*)(ws + 5505024);     // [5505024, 6029312)
  float* ef_g   = (float*)(ws + 6029312);     // [6029312, 6553600)

  float* sharing = (float*)d_out;
  float* effm    = sharing + (long)NB*NB;
  float* total   = effm + (long)NB*NB;
  float* esent   = total + 1;
  float* erecv   = esent + NB;
  float* nafter  = erecv + NB;

  hipLaunchKernelGGL(k_hijprio, dim3(530), dim3(256), 0, stream,
                     emb, gen, cons, fp_w1, fp_b1, fp_w2, ps_w1, ps_b1, ps_w2, ps_b2,
                     assign, hourp, hi, hj, net, prio, g, row_of, w1d_c, bzc, w2f, total);
  hipLaunchKernelGGL(k_pflow, dim3(256), dim3(512), 0, stream,
                     hi, hj, pos, w1d_c, bzc, w2f, fp_b2, fp_w3, fp_b3,
                     en_w1, en_b1, en_w2, en_b2, g, pf_g, ef_g);
  hipLaunchKernelGGL(k_greedy, dim3(128), dim3(256), 0, stream,
                     net, prio, g, pf_g, ef_g,
                     fl_c, ef_c, total, esent, erecv, nafter);
  hipLaunchKernelGGL(k_write, dim3(4096), dim3(256), 0, stream,
                     fl_c, ef_c, g, row_of, sharing, effm);
}

// Round 5
// 241.001 us; speedup vs baseline: 1.0267x; 1.0267x over previous
//
#include <hip/hip_runtime.h>
#include <math.h>

#define NB 4096
#define NC 128
#define NK 32
#define NE 128

typedef __bf16 bf16x8 __attribute__((ext_vector_type(8)));
typedef float floatx4 __attribute__((ext_vector_type(4)));

__device__ __forceinline__ float sigmoidf_(float x){
  if (x >= 0.f){ float z = expf(-x); return 1.f/(1.f+z); }
  float z = expf(x); return z/(1.f+z);
}
__device__ __forceinline__ float softplusf_(float x){
  return fmaxf(x, 0.f) + log1pf(expf(-fabsf(x)));
}
__device__ __forceinline__ unsigned int pack_bf16(float a, float b){
  unsigned short ua = __builtin_bit_cast(unsigned short, (__bf16)a);
  unsigned short ub = __builtin_bit_cast(unsigned short, (__bf16)b);
  return (unsigned int)ua | ((unsigned int)ub << 16);
}

// ================= K1: hij GEMM + prio MLP + grouping + consts + w2f (unchanged from R4) =====
__global__ void k_hijprio(const float* __restrict__ emb, const float* __restrict__ gen,
                          const float* __restrict__ cons, const float* __restrict__ fp_w1,
                          const float* __restrict__ fp_b1, const float* __restrict__ fp_w2,
                          const float* __restrict__ ps_w1, const float* __restrict__ ps_b1,
                          const float* __restrict__ ps_w2, const float* __restrict__ ps_b2,
                          const int* __restrict__ assign, const int* __restrict__ hourp,
                          float* __restrict__ hi, float* __restrict__ hj,
                          float* __restrict__ net, float* __restrict__ prio,
                          int* __restrict__ g, int* __restrict__ row_of,
                          float* __restrict__ w1d_c, float* __restrict__ bzc,
                          uint4* __restrict__ w2f, float* __restrict__ total){
  int bid = blockIdx.x;
  int t = threadIdx.x;
  if (bid < 512){
    __shared__ float es[8*132];
    __shared__ float wsm[32*132];     // ps_w1 row-major: wsm[q*132+e]
    __shared__ float wa_s[128*36];    // W1a column-chunk, stride 36: 16B-aligned + bank-uniform
    __shared__ float wb_s[128*36];    // W1b column-chunk
    int i0 = bid*8;
    for (int idx = t; idx < 8*128; idx += 256){
      int b = idx >> 7, e = idx & 127;
      es[b*132 + e] = emb[(i0 + b)*128 + e];
    }
    for (int idx = t; idx < 4096; idx += 256){
      int q = idx >> 7, e = idx & 127;          // read ps_w1[q*128+e] coalesced
      wsm[q*132 + e] = ps_w1[q*128 + e];
    }
    // ---- hij (f32, precision-critical; identical fmaf nesting, W1 values identical) ----
    int o = t & 127, half = t >> 7;
    float ai[4], aj[4];
#pragma unroll
    for (int r = 0; r < 4; ++r){ ai[r] = 0.f; aj[r] = 0.f; }
    for (int ch = 0; ch < 4; ++ch){
      int ec = ch << 5;                         // e-chunk base: 0,32,64,96
      if (ch) __syncthreads();                  // prev chunk's readers done before overwrite
      for (int idx = t; idx < 4096; idx += 256){
        int row = idx >> 5, e2 = idx & 31;      // coalesced: 32 consecutive floats per row
        wa_s[row*36 + e2] = fp_w1[row*258 + ec + e2];
        wb_s[row*36 + e2] = fp_w1[row*258 + 128 + ec + e2];
      }
      __syncthreads();                          // (ch==0 also covers es/wsm staging)
      const float* war = &wa_s[o*36];
      const float* wbr = &wb_s[o*36];
#pragma unroll
      for (int e2 = 0; e2 < 32; e2 += 4){
        float4 wav = *(const float4*)&war[e2];  // ds_read_b128
        float4 wbv = *(const float4*)&wbr[e2];
        float wa0 = wav.x, wa1 = wav.y, wa2 = wav.z, wa3 = wav.w;
        float wb0 = wbv.x, wb1 = wbv.y, wb2 = wbv.z, wb3 = wbv.w;
        int e = ec + e2;
#pragma unroll
        for (int r = 0; r < 4; ++r){
          float4 ev = *(const float4*)&es[(half*4 + r)*132 + e];
          ai[r] = fmaf(ev.x, wa0, fmaf(ev.y, wa1, fmaf(ev.z, wa2, fmaf(ev.w, wa3, ai[r]))));
          aj[r] = fmaf(ev.x, wb0, fmaf(ev.y, wb1, fmaf(ev.z, wb2, fmaf(ev.w, wb3, aj[r]))));
        }
      }
    }
#pragma unroll
    for (int r = 0; r < 4; ++r){
      int b = i0 + half*4 + r;
      hi[b*128 + o] = ai[r];                    // natural order — consumers gather via g
      hj[b*128 + o] = aj[r];
    }
    // ---- prio (f32 exact; same accumulation order; b128 streaming reads) ----
    {
      int bl = t >> 5, q = t & 31;
      int i = i0 + bl;
      float acc = ps_b1[q];
      const float* er = &es[bl*132];
      const float* wr = &wsm[q*132];
      for (int e = 0; e < 128; e += 4){
        float4 ev = *(const float4*)&er[e];
        float4 wv = *(const float4*)&wr[e];
        acc = fmaf(ev.x, wv.x, acc);
        acc = fmaf(ev.y, wv.y, acc);
        acc = fmaf(ev.z, wv.z, acc);
        acc = fmaf(ev.w, wv.w, acc);
      }
      float v = fmaxf(acc, 0.f) * ps_w2[q];
      for (int m = 16; m >= 1; m >>= 1) v += __shfl_xor(v, m, 32);
      if (q == 0){
        prio[i] = sigmoidf_(v + ps_b2[0]);
        int h = hourp[0];
        net[i] = gen[i*24 + h] - cons[i*24 + h];
      }
    }
  } else if (bid < 528){
    __shared__ int hist[NC];
    __shared__ int loc[256];
    int start = (bid - 512)*256;
    for (int c = t; c < NC; c += 256) hist[c] = 0;
    __syncthreads();
    for (int j = t; j < start; j += 256) atomicAdd(&hist[assign[j]], 1);
    int i = start + t;
    int c = assign[i];
    loc[t] = c;
    __syncthreads();
    int r = hist[c];
    for (int j = 0; j < 256; ++j) r += (j < t && loc[j] == c) ? 1 : 0;
    if (r >= NK) r = NK - 1;
    g[c*NK + r] = i;
    row_of[i] = c*NK + r;
  } else if (bid == 528){
    if (t < 128){
      float hour_f = (float)hourp[0] / 24.0f;
      w1d_c[t] = fp_w1[t*258 + 256];
      bzc[t]   = fmaf(hour_f, fp_w1[t*258 + 257], fp_b1[t]);
    }
    if (t == 128) total[0] = 0.f;
  } else {
    // W2 fragments: frag f=(nt*4+ks)*64+lane holds W2[o=nt*16+(lane&15)][ks*32+(lane>>4)*8 + 0..7]
    for (int ff = t; ff < 1024; ff += 256){
      int lane = ff & 63, fi = ff >> 6;
      int nt = fi >> 2, ks = fi & 3;
      int o = nt*16 + (lane & 15);
      int kb = ks*32 + (lane >> 4)*8;
      const float* src = fp_w2 + o*128 + kb;
      uint4 u;
      u.x = pack_bf16(src[0], src[1]);
      u.y = pack_bf16(src[2], src[3]);
      u.z = pack_bf16(src[4], src[5]);
      u.w = pack_bf16(src[6], src[7]);
      w2f[ff] = u;
    }
  }
}

// ================= K2a: pflow + eff on the FULL GPU (256 blocks, 2 per cluster; unchanged) ====
__global__ __launch_bounds__(512) void k_pflow(
    const float* __restrict__ hi, const float* __restrict__ hj,
    const float* __restrict__ pos, const float* __restrict__ w1d_c,
    const float* __restrict__ bzc, const uint4* __restrict__ w2f,
    const float* __restrict__ fp_b2, const float* __restrict__ fp_w3,
    const float* __restrict__ fp_b3, const float* __restrict__ en_w1,
    const float* __restrict__ en_b1, const float* __restrict__ en_w2,
    const float* __restrict__ en_b2, const int* __restrict__ g,
    float* __restrict__ pf_g, float* __restrict__ ef_g){
  __shared__ float px[32], py[32];
  __shared__ int gl[32];
  int t = threadIdx.x;
  int lane = t & 63, wv = t >> 6;
  int c = blockIdx.x >> 1, hb = blockIdx.x & 1;
  if (t < 32){
    int b = g[c*NK + t];
    gl[t] = b;
    px[t] = pos[2*b];
    py[t] = pos[2*b + 1];
  }
  __syncthreads();
  {
    int l16 = lane & 15, quad = lane >> 4;
    bf16x8 bfr[4][4];
#pragma unroll
    for (int nt = 0; nt < 4; ++nt)
#pragma unroll
      for (int ks = 0; ks < 4; ++ks)
        bfr[nt][ks] = __builtin_bit_cast(bf16x8, w2f[(nt*4 + ks)*64 + lane]);
    float b2v[4], w3v[4];
#pragma unroll
    for (int nt = 0; nt < 4; ++nt){
      b2v[nt] = fp_b2[nt*16 + l16];
      w3v[nt] = fp_w3[nt*16 + l16];
    }
    float b3 = fp_b3[0];
    const float4* wd4 = (const float4*)w1d_c;
    const float4* bz4 = (const float4*)bzc;
    for (int it = 0; it < 4; ++it){
      int tile = hb*32 + it*8 + wv;          // this block's half of the 64 tiles
      int i = tile >> 1, j0 = (tile & 1)*16;
      int j = j0 + l16;
      float dx = px[i] - px[j], dy = py[i] - py[j];
      float d = sqrtf(fmaf(dx, dx, dy*dy));
      const float4* hi4 = (const float4*)(hi + gl[i]*128);
      const float4* hj4 = (const float4*)(hj + gl[j]*128);
      bf16x8 af[4];
#pragma unroll
      for (int ks = 0; ks < 4; ++ks){
        int q8 = ks*8 + quad*2;
        float4 a0 = hi4[q8], a1 = hi4[q8 + 1];
        float4 b0 = hj4[q8], b1 = hj4[q8 + 1];
        float4 w0 = wd4[q8], w1 = wd4[q8 + 1];
        float4 z0 = bz4[q8], z1 = bz4[q8 + 1];
        float v0 = fmaxf(a0.x + b0.x + fmaf(d, w0.x, z0.x), 0.f);
        float v1 = fmaxf(a0.y + b0.y + fmaf(d, w0.y, z0.y), 0.f);
        float v2 = fmaxf(a0.z + b0.z + fmaf(d, w0.z, z0.z), 0.f);
        float v3 = fmaxf(a0.w + b0.w + fmaf(d, w0.w, z0.w), 0.f);
        float v4 = fmaxf(a1.x + b1.x + fmaf(d, w1.x, z1.x), 0.f);
        float v5 = fmaxf(a1.y + b1.y + fmaf(d, w1.y, z1.y), 0.f);
        float v6 = fmaxf(a1.z + b1.z + fmaf(d, w1.z, z1.z), 0.f);
        float v7 = fmaxf(a1.w + b1.w + fmaf(d, w1.w, z1.w), 0.f);
        uint4 u;
        u.x = pack_bf16(v0, v1);
        u.y = pack_bf16(v2, v3);
        u.z = pack_bf16(v4, v5);
        u.w = pack_bf16(v6, v7);
        af[ks] = __builtin_bit_cast(bf16x8, u);
      }
      floatx4 acc[4];
#pragma unroll
      for (int nt = 0; nt < 4; ++nt){
        acc[nt] = (floatx4){0.f, 0.f, 0.f, 0.f};
#pragma unroll
        for (int ks = 0; ks < 4; ++ks)
          acc[nt] = __builtin_amdgcn_mfma_f32_16x16x32_bf16(af[ks], bfr[nt][ks], acc[nt], 0, 0, 0);
      }
#pragma unroll
      for (int r = 0; r < 4; ++r){
        float s = 0.f;
#pragma unroll
        for (int nt = 0; nt < 4; ++nt)
          s = fmaf(fmaxf(acc[nt][r] + b2v[nt], 0.f), w3v[nt], s);
#pragma unroll
        for (int m = 8; m >= 1; m >>= 1) s += __shfl_xor(s, m);
        if (l16 == 0)
          pf_g[c*1024 + i*32 + j0 + quad*4 + r] = softplusf_(s + b3);
      }
    }
  }
  // ---- eff: this block's 512 entries (rows in its half), one per thread ----
  {
    int e = hb*512 + t;
    int ii = e >> 5, jj = e & 31;
    float dx = px[ii] - px[jj], dy = py[ii] - py[jj];
    float d = sqrtf(fmaf(dx, dx, dy*dy));
    float ds = d * (1.0f/1000.0f);
    float acc = en_b2[0];
#pragma unroll
    for (int q = 0; q < 16; ++q)
      acc = fmaf(fmaxf(fmaf(ds, en_w1[q], en_b1[q]), 0.f), en_w2[q], acc);
    ef_g[c*1024 + e] = 0.85f + 0.13f*sigmoidf_(acc);
  }
}

// ================= K2b: greedy + DIRECT output streaming (fused; replaces k_greedy+k_write) ===
// 256 blocks = 2 per cluster. Both halves run the (cheap) greedy identically — wall-time free,
// parallel CUs — so the 128MB output write uses the full GPU. Each half streams 16 of the
// cluster's 32 rows straight from registers: a per-thread match list (LDS scatter table,
// statically indexed) marks which of its 16 columns are in-cluster; everything else is the
// 0/1 default. Zero barriers and zero LDS fill in the streaming loop (old k_write drained
// vmcnt at 2 barriers per block). Store layout: instruction q covers columns q*1024+lane*4
// -> each wave store = 1KB contiguous. Global side-outputs guarded to half 0 (total's atomic
// must fire exactly once per cluster).
__global__ __launch_bounds__(256) void k_gw(
    const float* __restrict__ net, const float* __restrict__ prio,
    const int* __restrict__ g, const float* __restrict__ pf_g,
    const float* __restrict__ ef_g, float* __restrict__ total,
    float* __restrict__ esent, float* __restrict__ erecv, float* __restrict__ nafter,
    float* __restrict__ sharing, float* __restrict__ effm){
  __shared__ float pf_s[1024];
  __shared__ float ef_s[1024];
  __shared__ float fl_s[1024];
  __shared__ float efa_s[1024];
  __shared__ int   mtbl[NB];          // building -> in-cluster slot j (or -1)
  __shared__ int   gl[32];
  __shared__ int   order_s[32];
  int t = threadIdx.x;
  int c = blockIdx.x >> 1, hb = blockIdx.x & 1;
  if (t < 32) gl[t] = g[c*NK + t];
  // stage pf/eff (one float4 per thread each; coalesced, L2-hot)
  ((float4*)pf_s)[t] = ((const float4*)(pf_g + c*1024))[t];
  ((float4*)ef_s)[t] = ((const float4*)(ef_g + c*1024))[t];
#pragma unroll
  for (int q = 0; q < 16; ++q) mtbl[q*256 + t] = -1;
  __syncthreads();
  if (t < 32) mtbl[gl[t]] = t;
  if (t < 64){
    int tl = t & 31;
    float pr = (t < 32) ? prio[gl[t]] : -1e30f;
    int rank = 0;
    for (int k = 0; k < 32; ++k){
      float pk = __shfl(pr, k, 32);
      rank += ((pk > pr) || (pk == pr && k < tl)) ? 1 : 0;
    }
    if (t < 32) order_s[rank] = t;
  }
  __syncthreads();
  // ---- greedy allocation (decision math bit-identical to proven R2/R3 code) ----
  if (t < 64){
    int tl = t & 31;
    int b = order_s[tl];
    float net0 = net[gl[b]];
    float dnet = net0;
    float recv = 0.f;
    for (int i = 0; i < 32; ++i){
      int a = order_s[i];
      float av0 = fmaxf(__shfl(net0, i, 32), 0.f);
      float pf = pf_s[a*32 + b];
      float ef = ef_s[a*32 + b];
      float needed = -dnet;
      float m = (needed > 0.f) ? fminf(needed, pf) : 0.f;
      float s = m;
#pragma unroll
      for (int dd = 1; dd < 32; dd <<= 1){
        float u = __shfl_up(s, dd, 32);
        if (tl >= dd) s += u;
      }
      float Se = __shfl_up(s, 1, 32);
      if (tl == 0) Se = 0.f;
      float rprev = fmaxf(av0 - Se, 0.f);
      int act = (rprev > 0.f) && (needed > 0.f);
      float f = fminf(m, rprev);
      dnet = fmaf(f, ef, dnet);
      recv = fmaf(f, ef, recv);
      if (t < 32){
        fl_s[a*32 + b]  = f;
        efa_s[a*32 + b] = act ? ef : 1.0f;
      }
    }
    if (hb == 0 && t < 32){
      nafter[gl[b]] = dnet;
      erecv[gl[b]]  = recv;
    }
  }
  __syncthreads();
  // ---- side outputs: esent rows + total (half 0 only; same summation order as before) ----
  if (hb == 0 && t < 32){
    float rs = 0.f;
#pragma unroll
    for (int j = 0; j < 32; ++j)
      rs += fl_s[t*32 + ((j + t) & 31)];        // rotated -> conflict-free row sums
    esent[gl[t]] = rs;
    float cs = rs;
    for (int m = 16; m >= 1; m >>= 1) cs += __shfl_xor(cs, m, 32);
    if (t == 0) atomicAdd(total, cs);
  }
  // ---- stream this half's 16 rows x 2 matrices, registers -> nontemporal stores ----
  int mjq[16];
#pragma unroll
  for (int q = 0; q < 4; ++q)
#pragma unroll
    for (int x = 0; x < 4; ++x)
      mjq[q*4 + x] = mtbl[q*1024 + t*4 + x];
  for (int al = 0; al < 16; ++al){
    int a = hb*16 + al;
    long row = (long)gl[a] * NB;
    const float* flr = &fl_s[a*32];
    const float* efr = &efa_s[a*32];
    floatx4* gs = (floatx4*)(sharing + row);
    floatx4* ge = (floatx4*)(effm + row);
#pragma unroll
    for (int q = 0; q < 4; ++q){
      floatx4 vs = (floatx4){0.f, 0.f, 0.f, 0.f};
      floatx4 ve = (floatx4){1.f, 1.f, 1.f, 1.f};
#pragma unroll
      for (int x = 0; x < 4; ++x){
        int mj = mjq[q*4 + x];
        if (mj >= 0){ vs[x] = flr[mj]; ve[x] = efr[mj]; }
      }
      __builtin_nontemporal_store(vs, &gs[q*256 + t]);
      __builtin_nontemporal_store(ve, &ge[q*256 + t]);
    }
  }
}

extern "C" void kernel_launch(void* const* d_in, const int* in_sizes, int n_in,
                              void* d_out, int out_size, void* d_ws, size_t ws_size,
                              hipStream_t stream){
  (void)in_sizes; (void)n_in; (void)out_size; (void)ws_size;
  const float* emb   = (const float*)d_in[0];
  const float* gen   = (const float*)d_in[1];
  const float* cons  = (const float*)d_in[2];
  const float* pos   = (const float*)d_in[3];
  const float* fp_w1 = (const float*)d_in[4];
  const float* fp_b1 = (const float*)d_in[5];
  const float* fp_w2 = (const float*)d_in[6];
  const float* fp_b2 = (const float*)d_in[7];
  const float* fp_w3 = (const float*)d_in[8];
  const float* fp_b3 = (const float*)d_in[9];
  const float* en_w1 = (const float*)d_in[10];
  const float* en_b1 = (const float*)d_in[11];
  const float* en_w2 = (const float*)d_in[12];
  const float* en_b2 = (const float*)d_in[13];
  const float* ps_w1 = (const float*)d_in[14];
  const float* ps_b1 = (const float*)d_in[15];
  const float* ps_w2 = (const float*)d_in[16];
  const float* ps_b2 = (const float*)d_in[17];
  const int*   assign = (const int*)d_in[18];
  const int*   hourp  = (const int*)d_in[20];

  // Workspace map (audited, no overlaps):
  char* ws = (char*)d_ws;
  int*   g      = (int*)  (ws + 0);           // [0,       16384)
  int*   row_of = (int*)  (ws + 16384);       // [16384,   32768)  (written by k1, unused now)
  float* net    = (float*)(ws + 32768);       // [32768,   49152)
  float* prio   = (float*)(ws + 49152);       // [49152,   65536)
  float* w1d_c  = (float*)(ws + 65536);       // [65536,   66048)
  float* bzc    = (float*)(ws + 66048);       // [66048,   66560)
  uint4* w2f    = (uint4*)(ws + 131072);      // [131072,  147456)
  float* hi     = (float*)(ws + 262144);      // [262144,  2359296)
  float* hj     = (float*)(ws + 2359296);     // [2359296, 4456448)
  float* pf_g   = (float*)(ws + 5505024);     // [5505024, 6029312)
  float* ef_g   = (float*)(ws + 6029312);     // [6029312, 6553600)

  float* sharing = (float*)d_out;
  float* effm    = sharing + (long)NB*NB;
  float* total   = effm + (long)NB*NB;
  float* esent   = total + 1;
  float* erecv   = esent + NB;
  float* nafter  = erecv + NB;

  hipLaunchKernelGGL(k_hijprio, dim3(530), dim3(256), 0, stream,
                     emb, gen, cons, fp_w1, fp_b1, fp_w2, ps_w1, ps_b1, ps_w2, ps_b2,
                     assign, hourp, hi, hj, net, prio, g, row_of, w1d_c, bzc, w2f, total);
  hipLaunchKernelGGL(k_pflow, dim3(256), dim3(512), 0, stream,
                     hi, hj, pos, w1d_c, bzc, w2f, fp_b2, fp_w3, fp_b3,
                     en_w1, en_b1, en_w2, en_b2, g, pf_g, ef_g);
  hipLaunchKernelGGL(k_gw, dim3(256), dim3(256), 0, stream,
                     net, prio, g, pf_g, ef_g, total, esent, erecv, nafter,
                     sharing, effm);
}